// Round 1
// baseline (804.751 us; speedup 1.0000x reference)
//
#include <hip/hip_runtime.h>
#include <hip/hip_bf16.h>
#include <cstddef>

// Problem constants
#define BB 4
#define CC 512
#define TT 2048
#define NN 4096
#define HH 4
// d = CC/HH = 128

// qg scale: (1/sqrt(d)) * (1/sqrt(H)) = 1/(sqrt(128)*2)
constexpr float KFAC = 0.04419417382415922f;

// ---------------------------------------------------------------------------
// Kernel A: codebook projections  kproj = cb@Wk + bk,  vproj = cb@Wv + bv
// A[m=n][k=cin] = cb[n][cin] (transpose-staged), B[k][cout] = W[cin][cout]
// 128x128 tile, 8x8 microtile, K-chunk 16.
// ---------------------------------------------------------------------------
__global__ __launch_bounds__(256) void k_proj_codebook(
    const float* __restrict__ cb,
    const float* __restrict__ Wk, const float* __restrict__ bk,
    const float* __restrict__ Wv, const float* __restrict__ bv,
    float* __restrict__ kproj, float* __restrict__ vproj)
{
    const float* __restrict__ W    = blockIdx.z ? Wv : Wk;
    const float* __restrict__ bias = blockIdx.z ? bv : bk;
    float* __restrict__ out        = blockIdx.z ? vproj : kproj;
    const int m0 = blockIdx.y * 128;   // n rows
    const int n0 = blockIdx.x * 128;   // cout cols

    __shared__ __align__(16) float a_sh[16][136]; // [k][m] (transposed)
    __shared__ __align__(16) float b_sh[16][128]; // [k][cout]
    float acc[8][8] = {};
    const int tid = threadIdx.x;
    const int tx = tid & 15, ty = tid >> 4;

    for (int k0 = 0; k0 < CC; k0 += 16) {
        #pragma unroll
        for (int l = 0; l < 2; ++l) {
            int q = tid + l * 256;
            int am = q >> 2, ak = (q & 3) << 2;
            float4 va = *(const float4*)(cb + (size_t)(m0 + am) * CC + k0 + ak);
            a_sh[ak + 0][am] = va.x; a_sh[ak + 1][am] = va.y;
            a_sh[ak + 2][am] = va.z; a_sh[ak + 3][am] = va.w;
            int kk = q >> 5, ct = (q & 31) << 2;
            *(float4*)(&b_sh[kk][ct]) =
                *(const float4*)(W + (size_t)(k0 + kk) * CC + n0 + ct);
        }
        __syncthreads();
        #pragma unroll
        for (int k = 0; k < 16; ++k) {
            float4 a0 = *(const float4*)(&a_sh[k][ty * 8]);
            float4 a1 = *(const float4*)(&a_sh[k][ty * 8 + 4]);
            float4 b0 = *(const float4*)(&b_sh[k][tx * 8]);
            float4 b1 = *(const float4*)(&b_sh[k][tx * 8 + 4]);
            float av[8] = {a0.x, a0.y, a0.z, a0.w, a1.x, a1.y, a1.z, a1.w};
            float bw[8] = {b0.x, b0.y, b0.z, b0.w, b1.x, b1.y, b1.z, b1.w};
            #pragma unroll
            for (int r = 0; r < 8; ++r)
                #pragma unroll
                for (int c = 0; c < 8; ++c)
                    acc[r][c] = fmaf(av[r], bw[c], acc[r][c]);
        }
        __syncthreads();
    }
    #pragma unroll
    for (int r = 0; r < 8; ++r) {
        size_t row = (size_t)(m0 + ty * 8 + r) * CC + n0 + tx * 8;
        #pragma unroll
        for (int c = 0; c < 8; ++c)
            out[row + c] = acc[r][c] + bias[n0 + tx * 8 + c];
    }
}

// ---------------------------------------------------------------------------
// Kernel B: qgT[b][cout][t] = ((hs[b,:,t]@Wq)[cout] + bq[cout]) * cg[b,t,h] * KFAC
//   where cg[b,t,h] = hs[b,:,t]@Wp[:,h] + bp[h],  h = cout/128 (one head per
//   128-wide cout tile since d=128).
// A[k][cout] = Wq[k][cout] (direct), B[k][t] = hs[b][k][t] (direct).
// ---------------------------------------------------------------------------
__global__ __launch_bounds__(256) void k_proj_q(
    const float* __restrict__ hs,   // [B][C][T]
    const float* __restrict__ Wq, const float* __restrict__ bq,
    const float* __restrict__ Wp, const float* __restrict__ bp,
    float* __restrict__ qgT)        // [B][C][T]
{
    const int b  = blockIdx.z;
    const int m0 = blockIdx.x * 128;  // cout
    const int t0 = blockIdx.y * 128;  // t
    const int hblk = m0 >> 7;         // head index for this cout tile

    __shared__ __align__(16) float a_sh[16][128]; // Wq[k][cout]
    __shared__ __align__(16) float b_sh[16][128]; // hs[k][t]
    __shared__ float wp_sh[16];
    __shared__ float cg_sh[128];
    float acc[8][8] = {};
    float gate = 0.f;
    const int tid = threadIdx.x;
    const int tx = tid & 15, ty = tid >> 4;
    const float* hb = hs + (size_t)b * CC * TT;

    for (int k0 = 0; k0 < CC; k0 += 16) {
        #pragma unroll
        for (int l = 0; l < 2; ++l) {
            int q = tid + l * 256;
            int kk = q >> 5, ct = (q & 31) << 2;
            *(float4*)(&a_sh[kk][ct]) =
                *(const float4*)(Wq + (size_t)(k0 + kk) * CC + m0 + ct);
            *(float4*)(&b_sh[kk][ct]) =
                *(const float4*)(hb + (size_t)(k0 + kk) * TT + t0 + ct);
        }
        if (tid < 16) wp_sh[tid] = Wp[(size_t)(k0 + tid) * HH + hblk];
        __syncthreads();
        #pragma unroll
        for (int k = 0; k < 16; ++k) {
            float4 a0 = *(const float4*)(&a_sh[k][ty * 8]);
            float4 a1 = *(const float4*)(&a_sh[k][ty * 8 + 4]);
            float4 b0 = *(const float4*)(&b_sh[k][tx * 8]);
            float4 b1 = *(const float4*)(&b_sh[k][tx * 8 + 4]);
            float av[8] = {a0.x, a0.y, a0.z, a0.w, a1.x, a1.y, a1.z, a1.w};
            float bw[8] = {b0.x, b0.y, b0.z, b0.w, b1.x, b1.y, b1.z, b1.w};
            #pragma unroll
            for (int r = 0; r < 8; ++r)
                #pragma unroll
                for (int c = 0; c < 8; ++c)
                    acc[r][c] = fmaf(av[r], bw[c], acc[r][c]);
        }
        if (tid < 128) {
            #pragma unroll
            for (int k = 0; k < 16; ++k)
                gate = fmaf(b_sh[k][tid], wp_sh[k], gate);
        }
        __syncthreads();
    }
    if (tid < 128) cg_sh[tid] = (gate + bp[hblk]) * KFAC;
    __syncthreads();
    #pragma unroll
    for (int r = 0; r < 8; ++r) {
        int m = m0 + ty * 8 + r;
        float qb = bq[m];
        size_t row = ((size_t)b * CC + m) * TT + t0 + tx * 8;
        #pragma unroll
        for (int c = 0; c < 8; ++c)
            qgT[row + c] = (acc[r][c] + qb) * cg_sh[tx * 8 + c];
    }
}

// ---------------------------------------------------------------------------
// Kernel C: logits[b][n][t] = sum_c kproj[n][c] * qgT[b][c][t]
// A[m=n][k=c] = kproj (transpose-staged), B[k][t] = qgT[b] (direct).
// ---------------------------------------------------------------------------
__global__ __launch_bounds__(256) void k_logits(
    const float* __restrict__ kproj,  // [N][C]
    const float* __restrict__ qgT,    // [B][C][T]
    float* __restrict__ logits)       // [B][N][T]
{
    const int b  = blockIdx.z;
    const int n0 = blockIdx.y * 128;
    const int t0 = blockIdx.x * 128;

    __shared__ __align__(16) float a_sh[16][136]; // [k][n]
    __shared__ __align__(16) float b_sh[16][128]; // [k][t]
    float acc[8][8] = {};
    const int tid = threadIdx.x;
    const int tx = tid & 15, ty = tid >> 4;
    const float* qb = qgT + (size_t)b * CC * TT;

    for (int k0 = 0; k0 < CC; k0 += 16) {
        #pragma unroll
        for (int l = 0; l < 2; ++l) {
            int q = tid + l * 256;
            int am = q >> 2, ak = (q & 3) << 2;
            float4 va = *(const float4*)(kproj + (size_t)(n0 + am) * CC + k0 + ak);
            a_sh[ak + 0][am] = va.x; a_sh[ak + 1][am] = va.y;
            a_sh[ak + 2][am] = va.z; a_sh[ak + 3][am] = va.w;
            int kk = q >> 5, ct = (q & 31) << 2;
            *(float4*)(&b_sh[kk][ct]) =
                *(const float4*)(qb + (size_t)(k0 + kk) * TT + t0 + ct);
        }
        __syncthreads();
        #pragma unroll
        for (int k = 0; k < 16; ++k) {
            float4 a0 = *(const float4*)(&a_sh[k][ty * 8]);
            float4 a1 = *(const float4*)(&a_sh[k][ty * 8 + 4]);
            float4 b0 = *(const float4*)(&b_sh[k][tx * 8]);
            float4 b1 = *(const float4*)(&b_sh[k][tx * 8 + 4]);
            float av[8] = {a0.x, a0.y, a0.z, a0.w, a1.x, a1.y, a1.z, a1.w};
            float bw[8] = {b0.x, b0.y, b0.z, b0.w, b1.x, b1.y, b1.z, b1.w};
            #pragma unroll
            for (int r = 0; r < 8; ++r)
                #pragma unroll
                for (int c = 0; c < 8; ++c)
                    acc[r][c] = fmaf(av[r], bw[c], acc[r][c]);
        }
        __syncthreads();
    }
    #pragma unroll
    for (int r = 0; r < 8; ++r) {
        size_t row = ((size_t)b * NN + n0 + ty * 8 + r) * TT + t0 + tx * 8;
        *(float4*)(logits + row)     = make_float4(acc[r][0], acc[r][1], acc[r][2], acc[r][3]);
        *(float4*)(logits + row + 4) = make_float4(acc[r][4], acc[r][5], acc[r][6], acc[r][7]);
    }
}

// ---------------------------------------------------------------------------
// Kernel D: per (b,t): idx = argmax_n logits[b][n][t] (first-max tie-break,
// matches jnp/np argmax); z_q[b][:,t] = vproj[idx][:]; idx written as float.
// Block: 32 t-lanes x 8 n-chunks.
// ---------------------------------------------------------------------------
__global__ __launch_bounds__(256) void k_argmax_gather(
    const float* __restrict__ logits,  // [B][N][T]
    const float* __restrict__ vproj,   // [N][C]
    float* __restrict__ idx_out,       // [B][T] (float)
    float* __restrict__ zq)            // [B][C][T]
{
    const int b  = blockIdx.y;
    const int t0 = blockIdx.x * 32;
    const int tx = threadIdx.x & 31;   // t lane
    const int ty = threadIdx.x >> 5;   // n-chunk 0..7
    const float* base = logits + (size_t)b * NN * TT + t0 + tx;

    float best = -3.0e38f;
    int bi = ty * 512;
    #pragma unroll 4
    for (int n = ty * 512; n < ty * 512 + 512; ++n) {
        float v = base[(size_t)n * TT];
        if (v > best) { best = v; bi = n; }
    }

    __shared__ float sval[8][33];
    __shared__ int   sidx[8][33];
    __shared__ int   sfin[32];
    sval[ty][tx] = best;
    sidx[ty][tx] = bi;
    __syncthreads();
    if (ty == 0) {
        #pragma unroll
        for (int j = 1; j < 8; ++j) {
            float v = sval[j][tx];
            if (v > best) { best = v; bi = sidx[j][tx]; }  // strict >: first max wins
        }
        idx_out[(size_t)b * TT + t0 + tx] = (float)bi;
        sfin[tx] = bi;
    }
    __syncthreads();
    for (int pos = threadIdx.x; pos < 32 * CC; pos += 256) {
        int c = pos >> 5, tl = pos & 31;
        zq[((size_t)b * CC + c) * TT + t0 + tl] = vproj[(size_t)sfin[tl] * CC + c];
    }
}

// ---------------------------------------------------------------------------
extern "C" void kernel_launch(void* const* d_in, const int* in_sizes, int n_in,
                              void* d_out, int out_size, void* d_ws, size_t ws_size,
                              hipStream_t stream)
{
    (void)in_sizes; (void)n_in; (void)out_size; (void)ws_size;
    const float* hs = (const float*)d_in[0];
    const float* cb = (const float*)d_in[1];
    const float* Wq = (const float*)d_in[2];
    const float* bq = (const float*)d_in[3];
    const float* Wk = (const float*)d_in[4];
    const float* bk = (const float*)d_in[5];
    const float* Wv = (const float*)d_in[6];
    const float* bv = (const float*)d_in[7];
    const float* Wp = (const float*)d_in[8];
    const float* bp = (const float*)d_in[9];

    float* qgT   = (float*)d_ws;                    // B*C*T   = 4,194,304 f
    float* kproj = qgT + (size_t)BB * CC * TT;      // N*C     = 2,097,152 f
    float* vproj = kproj + (size_t)NN * CC;         // N*C     = 2,097,152 f

    float* logits = (float*)d_out;                  // B*N*T
    float* idxf   = logits + (size_t)BB * NN * TT;  // B*T
    float* zq     = idxf + (size_t)BB * TT;         // B*C*T

    k_proj_codebook<<<dim3(CC / 128, NN / 128, 2), 256, 0, stream>>>(
        cb, Wk, bk, Wv, bv, kproj, vproj);
    k_proj_q<<<dim3(CC / 128, TT / 128, BB), 256, 0, stream>>>(
        hs, Wq, bq, Wp, bp, qgT);
    k_logits<<<dim3(TT / 128, NN / 128, BB), 256, 0, stream>>>(
        kproj, qgT, logits);
    k_argmax_gather<<<dim3(TT / 32, BB), 256, 0, stream>>>(
        logits, vproj, idxf, zq);
}

// Round 2
// 537.968 us; speedup vs baseline: 1.4959x; 1.4959x over previous
//
#include <hip/hip_runtime.h>
#include <hip/hip_bf16.h>
#include <cstddef>
#include <cstdint>

// Problem constants
#define BB 4
#define CC 512
#define TT 2048
#define NN 4096
#define HH 4
// d = CC/HH = 128

// qg scale: (1/sqrt(d)) * (1/sqrt(H)) = 1/(sqrt(128)*2); x512 folded for fp16 split
constexpr float KFAC512 = 0.04419417382415922f * 512.0f;
constexpr float INV_SCALE2 = 1.0f / (512.0f * 512.0f);   // undo both x512 scales

typedef _Float16 f16x8 __attribute__((ext_vector_type(8)));
typedef float    f32x4 __attribute__((ext_vector_type(4)));

__device__ __forceinline__ void gld16(const void* g, void* s) {
    __builtin_amdgcn_global_load_lds(
        (const __attribute__((address_space(1))) void*)g,
        (__attribute__((address_space(3))) void*)s, 16, 0, 0);
}

// ---------------------------------------------------------------------------
// Kernel A: codebook projections.
//   z==0: khi/klo = split-fp16 of (cb@Wk + bk)*512, layout [N][C]
//   z==1: vproj   = cb@Wv + bv (fp32, for the z_q gather), layout [N][C]
// ---------------------------------------------------------------------------
__global__ __launch_bounds__(256) void k_proj_codebook(
    const float* __restrict__ cb,
    const float* __restrict__ Wk, const float* __restrict__ bk,
    const float* __restrict__ Wv, const float* __restrict__ bv,
    _Float16* __restrict__ khi, _Float16* __restrict__ klo,
    float* __restrict__ vproj)
{
    const float* __restrict__ W    = blockIdx.z ? Wv : Wk;
    const float* __restrict__ bias = blockIdx.z ? bv : bk;
    const int m0 = blockIdx.y * 128;   // n rows
    const int n0 = blockIdx.x * 128;   // cout cols

    __shared__ __align__(16) float a_sh[16][136]; // [k][m] (transposed)
    __shared__ __align__(16) float b_sh[16][128]; // [k][cout]
    float acc[8][8] = {};
    const int tid = threadIdx.x;
    const int tx = tid & 15, ty = tid >> 4;

    for (int k0 = 0; k0 < CC; k0 += 16) {
        #pragma unroll
        for (int l = 0; l < 2; ++l) {
            int q = tid + l * 256;
            int am = q >> 2, ak = (q & 3) << 2;
            float4 va = *(const float4*)(cb + (size_t)(m0 + am) * CC + k0 + ak);
            a_sh[ak + 0][am] = va.x; a_sh[ak + 1][am] = va.y;
            a_sh[ak + 2][am] = va.z; a_sh[ak + 3][am] = va.w;
            int kk = q >> 5, ct = (q & 31) << 2;
            *(float4*)(&b_sh[kk][ct]) =
                *(const float4*)(W + (size_t)(k0 + kk) * CC + n0 + ct);
        }
        __syncthreads();
        #pragma unroll
        for (int k = 0; k < 16; ++k) {
            float4 a0 = *(const float4*)(&a_sh[k][ty * 8]);
            float4 a1 = *(const float4*)(&a_sh[k][ty * 8 + 4]);
            float4 b0 = *(const float4*)(&b_sh[k][tx * 8]);
            float4 b1 = *(const float4*)(&b_sh[k][tx * 8 + 4]);
            float av[8] = {a0.x, a0.y, a0.z, a0.w, a1.x, a1.y, a1.z, a1.w};
            float bw[8] = {b0.x, b0.y, b0.z, b0.w, b1.x, b1.y, b1.z, b1.w};
            #pragma unroll
            for (int r = 0; r < 8; ++r)
                #pragma unroll
                for (int c = 0; c < 8; ++c)
                    acc[r][c] = fmaf(av[r], bw[c], acc[r][c]);
        }
        __syncthreads();
    }
    if (blockIdx.z == 0) {
        #pragma unroll
        for (int r = 0; r < 8; ++r) {
            size_t row = (size_t)(m0 + ty * 8 + r) * CC + n0 + tx * 8;
            f16x8 H, L;
            #pragma unroll
            for (int c = 0; c < 8; ++c) {
                float v = (acc[r][c] + bias[n0 + tx * 8 + c]) * 512.0f;
                _Float16 h = (_Float16)v;
                H[c] = h; L[c] = (_Float16)(v - (float)h);
            }
            *(f16x8*)(khi + row) = H;
            *(f16x8*)(klo + row) = L;
        }
    } else {
        #pragma unroll
        for (int r = 0; r < 8; ++r) {
            size_t row = (size_t)(m0 + ty * 8 + r) * CC + n0 + tx * 8;
            #pragma unroll
            for (int c = 0; c < 8; ++c)
                vproj[row + c] = acc[r][c] + bias[n0 + tx * 8 + c];
        }
    }
}

// ---------------------------------------------------------------------------
// Kernel B: qhi/qlo[b][t][c] = split-fp16 of ((hs[b,:,t]@Wq + bq)[c] * cg[b,t,h(c)] * KFAC * 512)
// Computed as D[t][cout] = sum_k hs[k][t] * Wq[k][cout]; output is [T][C]
// (c-contiguous) so k_logits can stage it with global_load_lds.
// A[k][t] = hs[b][k][t] (direct), B[k][cout] = Wq (direct).
// ---------------------------------------------------------------------------
__global__ __launch_bounds__(256) void k_proj_q(
    const float* __restrict__ hs,   // [B][C][T]
    const float* __restrict__ Wq, const float* __restrict__ bq,
    const float* __restrict__ Wp, const float* __restrict__ bp,
    _Float16* __restrict__ qhi, _Float16* __restrict__ qlo)  // [B][T][C]
{
    const int b  = blockIdx.z;
    const int t0 = blockIdx.x * 128;  // t rows
    const int c0 = blockIdx.y * 128;  // cout cols
    const int hblk = c0 >> 7;         // head for this cout tile (d=128)

    __shared__ __align__(16) float a_sh[16][128]; // hs[k][t]
    __shared__ __align__(16) float b_sh[16][128]; // Wq[k][cout]
    __shared__ float wp_sh[16];
    __shared__ float cg_sh[128];
    float acc[8][8] = {};
    float gate = 0.f;
    const int tid = threadIdx.x;
    const int tx = tid & 15, ty = tid >> 4;
    const float* hb = hs + (size_t)b * CC * TT;

    for (int k0 = 0; k0 < CC; k0 += 16) {
        #pragma unroll
        for (int l = 0; l < 2; ++l) {
            int q = tid + l * 256;
            int kk = q >> 5, ct = (q & 31) << 2;
            *(float4*)(&a_sh[kk][ct]) =
                *(const float4*)(hb + (size_t)(k0 + kk) * TT + t0 + ct);
            *(float4*)(&b_sh[kk][ct]) =
                *(const float4*)(Wq + (size_t)(k0 + kk) * CC + c0 + ct);
        }
        if (tid < 16) wp_sh[tid] = Wp[(size_t)(k0 + tid) * HH + hblk];
        __syncthreads();
        #pragma unroll
        for (int k = 0; k < 16; ++k) {
            float4 a0 = *(const float4*)(&a_sh[k][ty * 8]);     // t
            float4 a1 = *(const float4*)(&a_sh[k][ty * 8 + 4]);
            float4 b0 = *(const float4*)(&b_sh[k][tx * 8]);     // cout
            float4 b1 = *(const float4*)(&b_sh[k][tx * 8 + 4]);
            float av[8] = {a0.x, a0.y, a0.z, a0.w, a1.x, a1.y, a1.z, a1.w};
            float bw[8] = {b0.x, b0.y, b0.z, b0.w, b1.x, b1.y, b1.z, b1.w};
            #pragma unroll
            for (int r = 0; r < 8; ++r)
                #pragma unroll
                for (int c = 0; c < 8; ++c)
                    acc[r][c] = fmaf(av[r], bw[c], acc[r][c]);
        }
        if (tid < 128) {
            #pragma unroll
            for (int k = 0; k < 16; ++k)
                gate = fmaf(a_sh[k][tid], wp_sh[k], gate);  // gate per t
        }
        __syncthreads();
    }
    if (tid < 128) cg_sh[tid] = (gate + bp[hblk]) * KFAC512;
    __syncthreads();
    #pragma unroll
    for (int r = 0; r < 8; ++r) {
        int tloc = ty * 8 + r;
        float g = cg_sh[tloc];
        size_t row = ((size_t)b * TT + t0 + tloc) * CC + c0 + tx * 8;
        f16x8 H, L;
        #pragma unroll
        for (int c = 0; c < 8; ++c) {
            float v = (acc[r][c] + bq[c0 + tx * 8 + c]) * g;
            _Float16 h = (_Float16)v;
            H[c] = h; L[c] = (_Float16)(v - (float)h);
        }
        *(f16x8*)(qhi + row) = H;
        *(f16x8*)(qlo + row) = L;
    }
}

// ---------------------------------------------------------------------------
// Kernel C: logits[b][n][t] = (1/2^18) * sum_c (khi+klo)[n][c] * (qhi+qlo)[b][t][c]
// MFMA split-fp16: acc += Ah*Bh + Ah*Bl + Al*Bh  (ll term dropped, ~2^-22 rel)
// 128x128 tile, BK=32, 4 waves in 2x2, each wave 4x4 grid of 16x16x32 MFMAs.
// Staged via global_load_lds width 16 into [row][k] LDS (k-contiguous, both
// operands lane-order matches global_load_lds's base+lane*16 rule).
// ---------------------------------------------------------------------------
__global__ __launch_bounds__(256, 2) void k_logits_mfma(
    const _Float16* __restrict__ khi, const _Float16* __restrict__ klo,
    const _Float16* __restrict__ qhi, const _Float16* __restrict__ qlo,
    float* __restrict__ logits)       // [B][N][T]
{
    const int b  = blockIdx.z;
    const int t0 = blockIdx.x * 128;
    const int n0 = blockIdx.y * 128;

    __shared__ __align__(16) _Float16 Ah[128][32];  // kproj hi [n][k]
    __shared__ __align__(16) _Float16 Al[128][32];
    __shared__ __align__(16) _Float16 Bh[128][32];  // qT hi [t][k]
    __shared__ __align__(16) _Float16 Bl[128][32];

    const int tid  = threadIdx.x;
    const int w    = tid >> 6;        // wave 0..3
    const int l    = tid & 63;
    const int quad = l >> 4;
    const int l15  = l & 15;
    const int wm   = (w >> 1) * 64;   // n offset of this wave
    const int wn   = (w & 1) * 64;    // t offset
    const int rA   = l >> 2;          // staging row within 16-row group
    const int cA   = (l & 3) * 8;     // staging col (halves)

    // per-lane global source pointers (k0 added in loop)
    const _Float16* pAh = khi + (size_t)(n0 + w * 32 + rA) * CC + cA;
    const _Float16* pAl = klo + (size_t)(n0 + w * 32 + rA) * CC + cA;
    const _Float16* pBh = qhi + ((size_t)b * TT + t0 + w * 32 + rA) * CC + cA;
    const _Float16* pBl = qlo + ((size_t)b * TT + t0 + w * 32 + rA) * CC + cA;

    f32x4 acc[4][4];
    #pragma unroll
    for (int i = 0; i < 4; ++i)
        #pragma unroll
        for (int j = 0; j < 4; ++j)
            acc[i][j] = (f32x4){0.f, 0.f, 0.f, 0.f};

    for (int k0 = 0; k0 < CC; k0 += 32) {
        gld16(pAh + k0,           &Ah[w * 32][0]);
        gld16(pAh + k0 + 16 * CC, &Ah[w * 32 + 16][0]);
        gld16(pAl + k0,           &Al[w * 32][0]);
        gld16(pAl + k0 + 16 * CC, &Al[w * 32 + 16][0]);
        gld16(pBh + k0,           &Bh[w * 32][0]);
        gld16(pBh + k0 + 16 * CC, &Bh[w * 32 + 16][0]);
        gld16(pBl + k0,           &Bl[w * 32][0]);
        gld16(pBl + k0 + 16 * CC, &Bl[w * 32 + 16][0]);
        __syncthreads();

        f16x8 fah[4], fal[4], fbh[4], fbl[4];
        #pragma unroll
        for (int i = 0; i < 4; ++i) {
            fah[i] = *(const f16x8*)&Ah[wm + i * 16 + l15][quad * 8];
            fal[i] = *(const f16x8*)&Al[wm + i * 16 + l15][quad * 8];
            fbh[i] = *(const f16x8*)&Bh[wn + i * 16 + l15][quad * 8];
            fbl[i] = *(const f16x8*)&Bl[wn + i * 16 + l15][quad * 8];
        }
        #pragma unroll
        for (int i = 0; i < 4; ++i)
            #pragma unroll
            for (int j = 0; j < 4; ++j) {
                acc[i][j] = __builtin_amdgcn_mfma_f32_16x16x32_f16(fah[i], fbh[j], acc[i][j], 0, 0, 0);
                acc[i][j] = __builtin_amdgcn_mfma_f32_16x16x32_f16(fah[i], fbl[j], acc[i][j], 0, 0, 0);
                acc[i][j] = __builtin_amdgcn_mfma_f32_16x16x32_f16(fal[i], fbh[j], acc[i][j], 0, 0, 0);
            }
        __syncthreads();
    }

    // C/D layout: col = lane&15, row = quad*4 + reg  (within each 16x16 tile)
    #pragma unroll
    for (int i = 0; i < 4; ++i) {
        #pragma unroll
        for (int j = 0; j < 4; ++j) {
            int col = t0 + wn + j * 16 + l15;
            #pragma unroll
            for (int r = 0; r < 4; ++r) {
                int row = n0 + wm + i * 16 + quad * 4 + r;
                logits[((size_t)b * NN + row) * TT + col] = acc[i][j][r] * INV_SCALE2;
            }
        }
    }
}

// ---------------------------------------------------------------------------
// Kernel D: per (b,t): idx = argmax_n logits[b][n][t] (first-max tie-break);
// z_q[b][:,t] = vproj[idx][:]; idx written as float.
// ---------------------------------------------------------------------------
__global__ __launch_bounds__(256) void k_argmax_gather(
    const float* __restrict__ logits,  // [B][N][T]
    const float* __restrict__ vproj,   // [N][C]
    float* __restrict__ idx_out,       // [B][T] (float)
    float* __restrict__ zq)            // [B][C][T]
{
    const int b  = blockIdx.y;
    const int t0 = blockIdx.x * 32;
    const int tx = threadIdx.x & 31;   // t lane
    const int ty = threadIdx.x >> 5;   // n-chunk 0..7
    const float* base = logits + (size_t)b * NN * TT + t0 + tx;

    float best = -3.0e38f;
    int bi = ty * 512;
    #pragma unroll 4
    for (int n = ty * 512; n < ty * 512 + 512; ++n) {
        float v = base[(size_t)n * TT];
        if (v > best) { best = v; bi = n; }
    }

    __shared__ float sval[8][33];
    __shared__ int   sidx[8][33];
    __shared__ int   sfin[32];
    sval[ty][tx] = best;
    sidx[ty][tx] = bi;
    __syncthreads();
    if (ty == 0) {
        #pragma unroll
        for (int j = 1; j < 8; ++j) {
            float v = sval[j][tx];
            if (v > best) { best = v; bi = sidx[j][tx]; }  // strict >: first max wins
        }
        idx_out[(size_t)b * TT + t0 + tx] = (float)bi;
        sfin[tx] = bi;
    }
    __syncthreads();
    for (int pos = threadIdx.x; pos < 32 * CC; pos += 256) {
        int c = pos >> 5, tl = pos & 31;
        zq[((size_t)b * CC + c) * TT + t0 + tl] = vproj[(size_t)sfin[tl] * CC + c];
    }
}

// ---------------------------------------------------------------------------
extern "C" void kernel_launch(void* const* d_in, const int* in_sizes, int n_in,
                              void* d_out, int out_size, void* d_ws, size_t ws_size,
                              hipStream_t stream)
{
    (void)in_sizes; (void)n_in; (void)out_size; (void)ws_size;
    const float* hs = (const float*)d_in[0];
    const float* cb = (const float*)d_in[1];
    const float* Wq = (const float*)d_in[2];
    const float* bq = (const float*)d_in[3];
    const float* Wk = (const float*)d_in[4];
    const float* bk = (const float*)d_in[5];
    const float* Wv = (const float*)d_in[6];
    const float* bv = (const float*)d_in[7];
    const float* Wp = (const float*)d_in[8];
    const float* bp = (const float*)d_in[9];

    char* ws = (char*)d_ws;
    _Float16* qhi = (_Float16*)(ws);                         // B*T*C = 4,194,304 halves
    _Float16* qlo = (_Float16*)(ws + 8388608);
    _Float16* khi = (_Float16*)(ws + 16777216);              // N*C = 2,097,152 halves
    _Float16* klo = (_Float16*)(ws + 20971520);
    float*    vproj = (float*)(ws + 25165824);               // N*C fp32 (8 MB)

    float* logits = (float*)d_out;                  // B*N*T
    float* idxf   = logits + (size_t)BB * NN * TT;  // B*T
    float* zq     = idxf + (size_t)BB * TT;         // B*C*T

    k_proj_codebook<<<dim3(CC / 128, NN / 128, 2), 256, 0, stream>>>(
        cb, Wk, bk, Wv, bv, khi, klo, vproj);
    k_proj_q<<<dim3(TT / 128, CC / 128, BB), 256, 0, stream>>>(
        hs, Wq, bq, Wp, bp, qhi, qlo);
    k_logits_mfma<<<dim3(TT / 128, NN / 128, BB), 256, 0, stream>>>(
        khi, klo, qhi, qlo, logits);
    k_argmax_gather<<<dim3(TT / 32, BB), 256, 0, stream>>>(
        logits, vproj, idxf, zq);
}

// Round 5
// 401.172 us; speedup vs baseline: 2.0060x; 1.3410x over previous
//
#include <hip/hip_runtime.h>
#include <hip/hip_bf16.h>
#include <cstddef>
#include <cstdint>

// Problem constants
#define BB 4
#define CC 512
#define TT 2048
#define NN 4096
#define HH 4
// d = CC/HH = 128

constexpr float KFAC       = 0.04419417382415922f;           // 1/(sqrt(128)*2)
constexpr float INV_S18    = 1.0f / 262144.0f;               // 2^-18 (undo two x512)
constexpr float INV_SCALE2 = 1.0f / (512.0f * 512.0f);

typedef _Float16 f16x8 __attribute__((ext_vector_type(8)));
typedef _Float16 f16x4 __attribute__((ext_vector_type(4)));
typedef float    f32x4 __attribute__((ext_vector_type(4)));

__device__ __forceinline__ void gld16(const void* g, void* s) {
    __builtin_amdgcn_global_load_lds(
        (const __attribute__((address_space(1))) void*)g,
        (__attribute__((address_space(3))) void*)s, 16, 0, 0);
}

struct HL { _Float16 h, l; };
__device__ __forceinline__ HL split512(float x) {
    float v = x * 512.0f;
    _Float16 h = (_Float16)v;
    return { h, (_Float16)(v - (float)h) };
}

// ---------------------------------------------------------------------------
// Prep 1: elementwise split (x512) of cb [N][C] -> cbhi/cblo fp16 [N][C]
// ---------------------------------------------------------------------------
__global__ __launch_bounds__(256) void k_split(
    const float* __restrict__ src, _Float16* __restrict__ hi, _Float16* __restrict__ lo, int n4)
{
    int q = blockIdx.x * 256 + threadIdx.x;
    if (q >= n4) return;
    float4 v = *(const float4*)(src + (size_t)q * 4);
    f16x4 H, L;
    HL a = split512(v.x); H[0] = a.h; L[0] = a.l;
    HL b = split512(v.y); H[1] = b.h; L[1] = b.l;
    HL c = split512(v.z); H[2] = c.h; L[2] = c.l;
    HL d = split512(v.w); H[3] = d.h; L[3] = d.l;
    *(f16x4*)(hi + (size_t)q * 4) = H;
    *(f16x4*)(lo + (size_t)q * 4) = L;
}

// ---------------------------------------------------------------------------
// Prep 2: transpose + split (x512): src fp32 [R][S] -> dst hi/lo fp16 [S][R]
// 64x64 tiles. Used for hs (per batch: [C][T] -> [T][C]) and weights.
// ---------------------------------------------------------------------------
__device__ __forceinline__ void tsplit_body(
    const float* __restrict__ src, _Float16* __restrict__ hi, _Float16* __restrict__ lo,
    int S, int R, int r0, int s0)
{
    __shared__ float ls[64][65];
    const int tid = threadIdx.x;
    #pragma unroll
    for (int i = 0; i < 4; ++i) {
        int q = tid + i * 256;
        int row = q >> 4, c4 = (q & 15) * 4;
        float4 v = *(const float4*)(src + (size_t)(r0 + row) * S + s0 + c4);
        ls[row][c4] = v.x; ls[row][c4 + 1] = v.y;
        ls[row][c4 + 2] = v.z; ls[row][c4 + 3] = v.w;
    }
    __syncthreads();
    #pragma unroll
    for (int i = 0; i < 2; ++i) {
        int q = tid + i * 256;
        int orow = q >> 3, seg = (q & 7) * 8;
        f16x8 H, L;
        #pragma unroll
        for (int j = 0; j < 8; ++j) {
            HL s = split512(ls[seg + j][orow]);
            H[j] = s.h; L[j] = s.l;
        }
        size_t off = (size_t)(s0 + orow) * R + r0 + seg;
        *(f16x8*)(hi + off) = H;
        *(f16x8*)(lo + off) = L;
    }
}

__global__ __launch_bounds__(256) void k_tsplit(
    const float* __restrict__ src, _Float16* __restrict__ hi, _Float16* __restrict__ lo,
    long sbatch, long dbatch, int S, int R)
{
    src += (size_t)blockIdx.z * sbatch;
    hi  += (size_t)blockIdx.z * dbatch;
    lo  += (size_t)blockIdx.z * dbatch;
    tsplit_body(src, hi, lo, S, R, blockIdx.y * 64, blockIdx.x * 64);
}

// Weights: Wq/Wk/Wv [C][C] -> W^T hi/lo [C][C], selected by blockIdx.z
__global__ __launch_bounds__(256) void k_tsplit_w(
    const float* __restrict__ w0, const float* __restrict__ w1, const float* __restrict__ w2,
    _Float16* __restrict__ h0, _Float16* __restrict__ h1, _Float16* __restrict__ h2,
    _Float16* __restrict__ l0, _Float16* __restrict__ l1, _Float16* __restrict__ l2)
{
    const int z = blockIdx.z;
    const float* src = z == 0 ? w0 : z == 1 ? w1 : w2;
    _Float16* hi = z == 0 ? h0 : z == 1 ? h1 : h2;
    _Float16* lo = z == 0 ? l0 : z == 1 ? l1 : l2;
    tsplit_body(src, hi, lo, CC, CC, blockIdx.y * 64, blockIdx.x * 64);
}

// ---------------------------------------------------------------------------
// MFMA tile core: 128x128 output tile, BK=32, 4 waves (2x2), 4x4 16x16x32
// MFMAs per wave, 3-term split-fp16. A rows = output rows, B rows = output
// cols, both LDS-staged [row][k] via global_load_lds width 16.
// ---------------------------------------------------------------------------
#define MFMA_TILE_DECLS                                                       \
    __shared__ __align__(16) _Float16 Ah[128][32];                            \
    __shared__ __align__(16) _Float16 Al[128][32];                            \
    __shared__ __align__(16) _Float16 Bh[128][32];                            \
    __shared__ __align__(16) _Float16 Bl[128][32];                            \
    const int tid  = threadIdx.x;                                             \
    const int w    = tid >> 6;                                                \
    const int l    = tid & 63;                                                \
    const int quad = l >> 4;                                                  \
    const int l15  = l & 15;                                                  \
    const int wm   = (w >> 1) * 64;                                           \
    const int wn   = (w & 1) * 64;                                            \
    const int rA   = l >> 2;                                                  \
    const int cA   = (l & 3) * 8;                                             \
    f32x4 acc[4][4];                                                          \
    _Pragma("unroll") for (int i = 0; i < 4; ++i)                             \
        _Pragma("unroll") for (int j = 0; j < 4; ++j)                         \
            acc[i][j] = (f32x4){0.f, 0.f, 0.f, 0.f};

#define MFMA_TILE_STAGE(pAh, pAl, pBh, pBl, k0, srcStride)                    \
    gld16(pAh + k0,                    &Ah[w * 32][0]);                       \
    gld16(pAh + k0 + 16 * (srcStride), &Ah[w * 32 + 16][0]);                  \
    gld16(pAl + k0,                    &Al[w * 32][0]);                       \
    gld16(pAl + k0 + 16 * (srcStride), &Al[w * 32 + 16][0]);                  \
    gld16(pBh + k0,                    &Bh[w * 32][0]);                       \
    gld16(pBh + k0 + 16 * (srcStride), &Bh[w * 32 + 16][0]);                  \
    gld16(pBl + k0,                    &Bl[w * 32][0]);                       \
    gld16(pBl + k0 + 16 * (srcStride), &Bl[w * 32 + 16][0]);

#define MFMA_TILE_COMPUTE                                                     \
    {                                                                         \
        f16x8 fah[4], fal[4], fbh[4], fbl[4];                                 \
        _Pragma("unroll") for (int i = 0; i < 4; ++i) {                       \
            fah[i] = *(const f16x8*)&Ah[wm + i * 16 + l15][quad * 8];         \
            fal[i] = *(const f16x8*)&Al[wm + i * 16 + l15][quad * 8];         \
            fbh[i] = *(const f16x8*)&Bh[wn + i * 16 + l15][quad * 8];         \
            fbl[i] = *(const f16x8*)&Bl[wn + i * 16 + l15][quad * 8];         \
        }                                                                     \
        _Pragma("unroll") for (int i = 0; i < 4; ++i)                         \
            _Pragma("unroll") for (int j = 0; j < 4; ++j) {                   \
                acc[i][j] = __builtin_amdgcn_mfma_f32_16x16x32_f16(fah[i], fbh[j], acc[i][j], 0, 0, 0); \
                acc[i][j] = __builtin_amdgcn_mfma_f32_16x16x32_f16(fah[i], fbl[j], acc[i][j], 0, 0, 0); \
                acc[i][j] = __builtin_amdgcn_mfma_f32_16x16x32_f16(fal[i], fbh[j], acc[i][j], 0, 0, 0); \
            }                                                                 \
    }

// ---------------------------------------------------------------------------
// Codebook projections via MFMA. z=0: khi/klo = split((cb@Wk + bk)*512);
// z=1: vproj = cb@Wv + bv (fp32).
// ---------------------------------------------------------------------------
__global__ __launch_bounds__(256, 2) void k_proj_cb_mfma(
    const _Float16* __restrict__ cbhi, const _Float16* __restrict__ cblo,
    const _Float16* __restrict__ wkTh, const _Float16* __restrict__ wkTl,
    const _Float16* __restrict__ wvTh, const _Float16* __restrict__ wvTl,
    const float* __restrict__ bk, const float* __restrict__ bv,
    _Float16* __restrict__ khi, _Float16* __restrict__ klo, float* __restrict__ vproj)
{
    const int z  = blockIdx.z;
    const _Float16* bTh = z ? wvTh : wkTh;
    const _Float16* bTl = z ? wvTl : wkTl;
    const float* bias   = z ? bv : bk;
    const int m0 = blockIdx.y * 128;   // n rows
    const int c0 = blockIdx.x * 128;   // cout

    MFMA_TILE_DECLS
    const _Float16* pAh = cbhi + (size_t)(m0 + w * 32 + rA) * CC + cA;
    const _Float16* pAl = cblo + (size_t)(m0 + w * 32 + rA) * CC + cA;
    const _Float16* pBh = bTh  + (size_t)(c0 + w * 32 + rA) * CC + cA;
    const _Float16* pBl = bTl  + (size_t)(c0 + w * 32 + rA) * CC + cA;

    for (int k0 = 0; k0 < CC; k0 += 32) {
        MFMA_TILE_STAGE(pAh, pAl, pBh, pBl, k0, CC)
        __syncthreads();
        MFMA_TILE_COMPUTE
        __syncthreads();
    }

    if (z == 0) {
        #pragma unroll
        for (int i = 0; i < 4; ++i)
            #pragma unroll
            for (int j = 0; j < 4; ++j) {
                int col = c0 + wn + j * 16 + l15;
                float bi = bias[col];
                #pragma unroll
                for (int r = 0; r < 4; ++r) {
                    int row = m0 + wm + i * 16 + quad * 4 + r;
                    float v = fmaf(acc[i][j][r], INV_S18, bi);
                    HL s = split512(v);
                    khi[(size_t)row * CC + col] = s.h;
                    klo[(size_t)row * CC + col] = s.l;
                }
            }
    } else {
        #pragma unroll
        for (int i = 0; i < 4; ++i)
            #pragma unroll
            for (int j = 0; j < 4; ++j) {
                int col = c0 + wn + j * 16 + l15;
                float bi = bias[col];
                #pragma unroll
                for (int r = 0; r < 4; ++r) {
                    int row = m0 + wm + i * 16 + quad * 4 + r;
                    vproj[(size_t)row * CC + col] = fmaf(acc[i][j][r], INV_S18, bi);
                }
            }
    }
}

// ---------------------------------------------------------------------------
// Q projection + gate via MFMA.
// v = ((hsT@Wq)[m][c] + bq[c]) * cg[m,h(c)] * KFAC;  qhi/qlo = split512(v)
// (split512 supplies the x512 the logits GEMM expects -- gate uses plain KFAC)
// where m = b*T+t (hsT is [B*T][C]), cg = hsT@Wp[:,h] + bp[h].
// ---------------------------------------------------------------------------
__global__ __launch_bounds__(256, 2) void k_proj_q_mfma(
    const _Float16* __restrict__ ah_g, const _Float16* __restrict__ al_g,  // hsT split
    const _Float16* __restrict__ wqTh, const _Float16* __restrict__ wqTl,
    const float* __restrict__ bq, const float* __restrict__ Wp, const float* __restrict__ bp,
    _Float16* __restrict__ qhi, _Float16* __restrict__ qlo)
{
    const int m0   = blockIdx.y * 128;  // b*T + t rows
    const int c0   = blockIdx.x * 128;  // cout
    const int hblk = c0 >> 7;           // head (d=128)

    MFMA_TILE_DECLS
    __shared__ float wp_sh[32];
    __shared__ float gate_sh[128];
    float gate = 0.f;

    const _Float16* pAh = ah_g + (size_t)(m0 + w * 32 + rA) * CC + cA;
    const _Float16* pAl = al_g + (size_t)(m0 + w * 32 + rA) * CC + cA;
    const _Float16* pBh = wqTh + (size_t)(c0 + w * 32 + rA) * CC + cA;
    const _Float16* pBl = wqTl + (size_t)(c0 + w * 32 + rA) * CC + cA;

    for (int k0 = 0; k0 < CC; k0 += 32) {
        MFMA_TILE_STAGE(pAh, pAl, pBh, pBl, k0, CC)
        if (tid < 32) wp_sh[tid] = Wp[(size_t)(k0 + tid) * HH + hblk];
        __syncthreads();
        MFMA_TILE_COMPUTE
        if (tid < 128) {
            #pragma unroll
            for (int s = 0; s < 4; ++s) {
                f16x8 hv = *(const f16x8*)&Ah[tid][s * 8];
                f16x8 lv = *(const f16x8*)&Al[tid][s * 8];
                #pragma unroll
                for (int jj = 0; jj < 8; ++jj)
                    gate = fmaf((float)hv[jj] + (float)lv[jj], wp_sh[s * 8 + jj], gate);
            }
        }
        __syncthreads();
    }
    if (tid < 128)
        gate_sh[tid] = (gate * (1.0f / 512.0f) + bp[hblk]) * KFAC;  // plain KFAC: split512 adds the x512
    __syncthreads();

    #pragma unroll
    for (int i = 0; i < 4; ++i)
        #pragma unroll
        for (int j = 0; j < 4; ++j) {
            int col = c0 + wn + j * 16 + l15;
            float bi = bq[col];
            #pragma unroll
            for (int r = 0; r < 4; ++r) {
                int rloc = wm + i * 16 + quad * 4 + r;
                float v = fmaf(acc[i][j][r], INV_S18, bi) * gate_sh[rloc];
                HL s = split512(v);
                qhi[(size_t)(m0 + rloc) * CC + col] = s.h;
                qlo[(size_t)(m0 + rloc) * CC + col] = s.l;
            }
        }
}

// ---------------------------------------------------------------------------
// logits[b][n][t] = 2^-18 * sum_c (khi+klo)[n][c] * (qhi+qlo)[b*T+t][c]
// ---------------------------------------------------------------------------
__global__ __launch_bounds__(256, 2) void k_logits_mfma(
    const _Float16* __restrict__ khi, const _Float16* __restrict__ klo,
    const _Float16* __restrict__ qhi, const _Float16* __restrict__ qlo,
    float* __restrict__ logits)       // [B][N][T]
{
    const int b  = blockIdx.z;
    const int t0 = blockIdx.x * 128;
    const int n0 = blockIdx.y * 128;

    MFMA_TILE_DECLS
    const _Float16* pAh = khi + (size_t)(n0 + w * 32 + rA) * CC + cA;
    const _Float16* pAl = klo + (size_t)(n0 + w * 32 + rA) * CC + cA;
    const _Float16* pBh = qhi + ((size_t)b * TT + t0 + w * 32 + rA) * CC + cA;
    const _Float16* pBl = qlo + ((size_t)b * TT + t0 + w * 32 + rA) * CC + cA;

    for (int k0 = 0; k0 < CC; k0 += 32) {
        MFMA_TILE_STAGE(pAh, pAl, pBh, pBl, k0, CC)
        __syncthreads();
        MFMA_TILE_COMPUTE
        __syncthreads();
    }

    #pragma unroll
    for (int i = 0; i < 4; ++i)
        #pragma unroll
        for (int j = 0; j < 4; ++j) {
            int col = t0 + wn + j * 16 + l15;
            #pragma unroll
            for (int r = 0; r < 4; ++r) {
                int row = n0 + wm + i * 16 + quad * 4 + r;
                logits[((size_t)b * NN + row) * TT + col] = acc[i][j][r] * INV_SCALE2;
            }
        }
}

// ---------------------------------------------------------------------------
// argmax over n + gather z_q rows. First-max tie-break (matches np).
// ---------------------------------------------------------------------------
__global__ __launch_bounds__(256) void k_argmax_gather(
    const float* __restrict__ logits,  // [B][N][T]
    const float* __restrict__ vproj,   // [N][C]
    float* __restrict__ idx_out,       // [B][T] (float)
    float* __restrict__ zq)            // [B][C][T]
{
    const int b  = blockIdx.y;
    const int t0 = blockIdx.x * 32;
    const int tx = threadIdx.x & 31;
    const int ty = threadIdx.x >> 5;
    const float* base = logits + (size_t)b * NN * TT + t0 + tx;

    float best = -3.0e38f;
    int bi = ty * 512;
    #pragma unroll 4
    for (int n = ty * 512; n < ty * 512 + 512; ++n) {
        float v = base[(size_t)n * TT];
        if (v > best) { best = v; bi = n; }
    }

    __shared__ float sval[8][33];
    __shared__ int   sidx[8][33];
    __shared__ int   sfin[32];
    sval[ty][tx] = best;
    sidx[ty][tx] = bi;
    __syncthreads();
    if (ty == 0) {
        #pragma unroll
        for (int j = 1; j < 8; ++j) {
            float v = sval[j][tx];
            if (v > best) { best = v; bi = sidx[j][tx]; }
        }
        idx_out[(size_t)b * TT + t0 + tx] = (float)bi;
        sfin[tx] = bi;
    }
    __syncthreads();
    for (int pos = threadIdx.x; pos < 32 * CC; pos += 256) {
        int c = pos >> 5, tl = pos & 31;
        zq[((size_t)b * CC + c) * TT + t0 + tl] = vproj[(size_t)sfin[tl] * CC + c];
    }
}

// ---------------------------------------------------------------------------
extern "C" void kernel_launch(void* const* d_in, const int* in_sizes, int n_in,
                              void* d_out, int out_size, void* d_ws, size_t ws_size,
                              hipStream_t stream)
{
    (void)in_sizes; (void)n_in; (void)out_size; (void)ws_size;
    const float* hs = (const float*)d_in[0];
    const float* cb = (const float*)d_in[1];
    const float* Wq = (const float*)d_in[2];
    const float* bq = (const float*)d_in[3];
    const float* Wk = (const float*)d_in[4];
    const float* bk = (const float*)d_in[5];
    const float* Wv = (const float*)d_in[6];
    const float* bv = (const float*)d_in[7];
    const float* Wp = (const float*)d_in[8];
    const float* bp = (const float*)d_in[9];

    char* ws = (char*)d_ws;
    const size_t MB = 1024 * 1024;
    _Float16* hsTh = (_Float16*)(ws);              // [B*T][C] 8 MB
    _Float16* hsTl = (_Float16*)(ws + 8  * MB);
    _Float16* qhi  = (_Float16*)(ws + 16 * MB);    // [B*T][C] 8 MB
    _Float16* qlo  = (_Float16*)(ws + 24 * MB);
    _Float16* cbhi = (_Float16*)(ws + 32 * MB);    // [N][C]   4 MB
    _Float16* cblo = (_Float16*)(ws + 36 * MB);
    _Float16* khi  = (_Float16*)(ws + 40 * MB);    // [N][C]   4 MB
    _Float16* klo  = (_Float16*)(ws + 44 * MB);
    float*    vproj= (float*)   (ws + 48 * MB);    // [N][C]   8 MB fp32
    _Float16* wqTh = (_Float16*)(ws + 56 * MB);    // [C][C]   0.5 MB each
    _Float16* wqTl = (_Float16*)(ws + 56 * MB + 524288);
    _Float16* wkTh = (_Float16*)(ws + 57 * MB);
    _Float16* wkTl = (_Float16*)(ws + 57 * MB + 524288);
    _Float16* wvTh = (_Float16*)(ws + 58 * MB);
    _Float16* wvTl = (_Float16*)(ws + 58 * MB + 524288);

    float* logits = (float*)d_out;                  // B*N*T
    float* idxf   = logits + (size_t)BB * NN * TT;  // B*T
    float* zq     = idxf + (size_t)BB * TT;         // B*C*T

    // Prep
    k_split<<<dim3((NN * CC / 4 + 255) / 256), 256, 0, stream>>>(
        cb, cbhi, cblo, NN * CC / 4);
    k_tsplit<<<dim3(TT / 64, CC / 64, BB), 256, 0, stream>>>(
        hs, hsTh, hsTl, (long)CC * TT, (long)TT * CC, TT, CC);
    k_tsplit_w<<<dim3(CC / 64, CC / 64, 3), 256, 0, stream>>>(
        Wq, Wk, Wv, wqTh, wkTh, wvTh, wqTl, wkTl, wvTl);

    // Projections (MFMA)
    k_proj_cb_mfma<<<dim3(CC / 128, NN / 128, 2), 256, 0, stream>>>(
        cbhi, cblo, wkTh, wkTl, wvTh, wvTl, bk, bv, khi, klo, vproj);
    k_proj_q_mfma<<<dim3(CC / 128, (BB * TT) / 128), 256, 0, stream>>>(
        hsTh, hsTl, wqTh, wqTl, bq, Wp, bp, qhi, qlo);

    // Logits (MFMA)
    k_logits_mfma<<<dim3(TT / 128, NN / 128, BB), 256, 0, stream>>>(
        khi, klo, qhi, qlo, logits);

    // Argmax + gather
    k_argmax_gather<<<dim3(TT / 32, BB), 256, 0, stream>>>(
        logits, vproj, idxf, zq);
}